// Round 4
// baseline (650.330 us; speedup 1.0000x reference)
//
#include <hip/hip_runtime.h>
#include <math.h>

#define KCODES 1024
#define DDIM   256
#define NROWS  65536
#define BM     64
#define NT     512

typedef float f4 __attribute__((ext_vector_type(4)));

// LDS layout for the z-tile: element (d, r) at
//   d*64 + ((r>>2) ^ ((d>>2)&15))*4 + (r&3)
// Inner-loop read (fixed d, row-group g): b128 at ((g ^ tt)<<2) — wave-uniform
// address -> LDS broadcast, conflict-free.
__device__ __forceinline__ int swz(int d, int r) {
    return (d << 6) + ((((r) >> 2) ^ ((d >> 2) & 15)) << 2) + (r & 3);
}

// ||e_k||^2 sequential over d (matches np axis-0 row-by-row reduce) + zero loss acc
__global__ __launch_bounds__(256) void enorm_kernel(const float* __restrict__ e,
                                                    float* __restrict__ enorm,
                                                    float* __restrict__ loss_acc) {
    const int k = blockIdx.x * 256 + threadIdx.x;
    if (k == 0) *loss_acc = 0.f;
    float s = 0.f;
    for (int d = 0; d < DDIM; ++d) {
        const float v = e[(size_t)d * KCODES + k];
        s = __fadd_rn(s, __fmul_rn(v, v));
    }
    enorm[k] = s;
}

// LDS-tiled transpose: eT[k][d] = e[d][k]; f4 reads AND f4 writes (one-time)
__global__ __launch_bounds__(256) void etrans_kernel(const float* __restrict__ e,
                                                     float* __restrict__ eT) {
    __shared__ float tile[64][65];
    const int k0 = blockIdx.x << 6;
    const int d0 = blockIdx.y << 6;
    const int tr = threadIdx.x >> 4;
    const int tc = threadIdx.x & 15;
    #pragma unroll
    for (int p = 0; p < 4; ++p) {
        const int d = (p << 4) + tr;
        const f4 v = *reinterpret_cast<const f4*>(e + (size_t)(d0 + d) * KCODES + k0 + (tc << 2));
        tile[(tc << 2) + 0][d] = v[0];
        tile[(tc << 2) + 1][d] = v[1];
        tile[(tc << 2) + 2][d] = v[2];
        tile[(tc << 2) + 3][d] = v[3];
    }
    __syncthreads();
    #pragma unroll
    for (int p = 0; p < 4; ++p) {
        const int k = (p << 4) + tr;
        f4 w;
        w[0] = tile[k][(tc << 2) + 0];
        w[1] = tile[k][(tc << 2) + 1];
        w[2] = tile[k][(tc << 2) + 2];
        w[3] = tile[k][(tc << 2) + 3];
        *reinterpret_cast<f4*>(eT + (size_t)(k0 + k) * DDIM + d0 + (tc << 2)) = w;
    }
}

__global__ __launch_bounds__(NT, 4) void vq_main(const float* __restrict__ z,
                                                 const float* __restrict__ e,
                                                 const float* __restrict__ enorm,
                                                 const float* __restrict__ eT,
                                                 float* __restrict__ out_zq,
                                                 float* __restrict__ out_idx,
                                                 float* __restrict__ loss_acc) {
    __shared__ __align__(16) float A[DDIM * BM];  // 64 KiB z-tile, swizzled
    __shared__ float zn_s[BM];
    __shared__ int   kmin_s[BM];
    __shared__ float wsum_s[8];

    const int tid  = threadIdx.x;
    const int lane = tid & 63;
    const int wv   = tid >> 6;          // wave 0..7
    const int row0 = blockIdx.x * BM;

    // ---- stage z tile (plain loads; wave reads 1 KiB contiguous per pass) ----
    for (int p = 0; p < 8; ++p) {
        const int row = p * 8 + wv;
        const int d0  = lane * 4;
        const f4 v = *reinterpret_cast<const f4*>(z + (size_t)(row0 + row) * DDIM + d0);
        A[swz(d0 + 0, row)] = v[0];
        A[swz(d0 + 1, row)] = v[1];
        A[swz(d0 + 2, row)] = v[2];
        A[swz(d0 + 3, row)] = v[3];
    }
    __syncthreads();

    // ---- ||z||^2 per row, numpy pairwise order (two 128-halves, 8 stride-8 partials) ----
    if (tid < BM) {
        const int r = tid;
        float hsum[2];
        #pragma unroll
        for (int h = 0; h < 2; ++h) {
            const int base = h * 128;
            float rp[8];
            #pragma unroll
            for (int j = 0; j < 8; ++j) {
                const float v = A[swz(base + j, r)];
                rp[j] = __fmul_rn(v, v);
            }
            for (int i = 8; i < 128; i += 8) {
                #pragma unroll
                for (int j = 0; j < 8; ++j) {
                    const float v = A[swz(base + i + j, r)];
                    rp[j] = __fadd_rn(rp[j], __fmul_rn(v, v));
                }
            }
            hsum[h] = __fadd_rn(__fadd_rn(__fadd_rn(rp[0], rp[1]), __fadd_rn(rp[2], rp[3])),
                                __fadd_rn(__fadd_rn(rp[4], rp[5]), __fadd_rn(rp[6], rp[7])));
        }
        zn_s[r] = __fadd_rn(hsum[0], hsum[1]);
    }
    __syncthreads();

    // ---- fused GEMM + running argmin ----
    // wave wv owns rows wv*8..wv*8+7 (A = 2 broadcast b128/d); lane owns 8 cols/d
    // across two 256-wide panels; 2 ct iterations cover K=1024.
    float rmin[8] = {INFINITY, INFINITY, INFINITY, INFINITY,
                     INFINITY, INFINITY, INFINITY, INFINITY};
    int   ridx[8] = {0, 0, 0, 0, 0, 0, 0, 0};

    const int g0 = wv << 1;            // row-group of rows wv*8..+3
    for (int ct = 0; ct < 2; ++ct) {
        const int cbase = ct << 9;     // 0, 512
        const char* bp = (const char*)(e + cbase + (lane << 2));

        float acc[8][8];               // [row][panel*4 + i]
        #pragma unroll
        for (int r = 0; r < 8; ++r)
            #pragma unroll
            for (int i = 0; i < 8; ++i) acc[r][i] = 0.f;

        for (int db = 0; db < DDIM; db += 2) {
            f4 b0[2], b1[2];
            #pragma unroll
            for (int j = 0; j < 2; ++j) {
                const size_t off = (size_t)(db + j) << 12;          // d rows of 4096 B
                b0[j] = *reinterpret_cast<const f4*>(bp + off);
                b1[j] = *reinterpret_cast<const f4*>(bp + off + 1024); // +256 cols
            }
            #pragma unroll
            for (int j = 0; j < 2; ++j) {
                const int d  = db + j;
                const int tt = (d >> 2) & 15;
                const f4 a0 = *reinterpret_cast<const f4*>(&A[(d << 6) + (((g0 | 0) ^ tt) << 2)]);
                const f4 a1 = *reinterpret_cast<const f4*>(&A[(d << 6) + (((g0 | 1) ^ tt) << 2)]);
                #pragma unroll
                for (int r = 0; r < 4; ++r) {
                    #pragma unroll
                    for (int i = 0; i < 4; ++i) {
                        acc[r][i]         = fmaf(a0[r], b0[j][i], acc[r][i]);
                        acc[r][4 + i]     = fmaf(a0[r], b1[j][i], acc[r][4 + i]);
                        acc[4 + r][i]     = fmaf(a1[r], b0[j][i], acc[4 + r][i]);
                        acc[4 + r][4 + i] = fmaf(a1[r], b1[j][i], acc[4 + r][4 + i]);
                    }
                }
            }
        }

        // epilogue: s = fl(fl(zn + en) - 2*dot); candidates ascend per thread
        // (panel 0 cols < panel 1 cols; ct=0 < ct=1), so strict < = first-min
        const f4 en0 = *reinterpret_cast<const f4*>(enorm + cbase + (lane << 2));
        const f4 en1 = *reinterpret_cast<const f4*>(enorm + cbase + 256 + (lane << 2));
        #pragma unroll
        for (int r8 = 0; r8 < 8; ++r8) {
            const float zn = zn_s[(wv << 3) + r8];
            #pragma unroll
            for (int p = 0; p < 2; ++p) {
                const f4 en = p ? en1 : en0;
                const int cc = cbase + (p << 8) + (lane << 2);
                #pragma unroll
                for (int i = 0; i < 4; ++i) {
                    const float t = __fadd_rn(zn, en[i]);
                    const float s = __fmaf_rn(-2.f, acc[r8][(p << 2) + i], t);
                    if (s < rmin[r8]) { rmin[r8] = s; ridx[r8] = cc + i; }
                }
            }
        }
    }

    // ---- per-row argmin reduce across 64 lanes (value, then min index on ties) ----
    #pragma unroll
    for (int r8 = 0; r8 < 8; ++r8) {
        float bv = rmin[r8];
        int   bi = ridx[r8];
        #pragma unroll
        for (int mask = 32; mask >= 1; mask >>= 1) {
            const float ov = __shfl_xor(bv, mask);
            const int   oi = __shfl_xor(bi, mask);
            if (ov < bv || (ov == bv && oi < bi)) { bv = ov; bi = oi; }
        }
        if (lane == 0) {
            const int row = (wv << 3) + r8;
            kmin_s[row] = bi;
            out_idx[row0 + row] = (float)bi;
        }
    }
    __syncthreads();

    // ---- gather z_q rows (coalesced via eT), write out, accumulate loss ----
    float part = 0.f;
    for (int p = 0; p < 8; ++p) {
        const int row = p * 8 + wv;
        const int d0  = lane * 4;
        const int kk  = kmin_s[row];
        const f4 q = *reinterpret_cast<const f4*>(eT + (size_t)kk * DDIM + d0);
        const float z0 = A[swz(d0 + 0, row)];
        const float z1 = A[swz(d0 + 1, row)];
        const float z2 = A[swz(d0 + 2, row)];
        const float z3 = A[swz(d0 + 3, row)];
        float dx;
        dx = q[0] - z0; part = fmaf(dx, dx, part);
        dx = q[1] - z1; part = fmaf(dx, dx, part);
        dx = q[2] - z2; part = fmaf(dx, dx, part);
        dx = q[3] - z3; part = fmaf(dx, dx, part);
        *reinterpret_cast<f4*>(out_zq + (size_t)(row0 + row) * DDIM + d0) = q;
    }
    #pragma unroll
    for (int off = 32; off > 0; off >>= 1) part += __shfl_down(part, off);
    if (lane == 0) wsum_s[wv] = part;
    __syncthreads();
    if (tid == 0) {
        float s = 0.f;
        #pragma unroll
        for (int i = 0; i < 8; ++i) s += wsum_s[i];
        atomicAdd(loss_acc, s);
    }
}

__global__ void finalize_kernel(const float* __restrict__ loss_acc,
                                float* __restrict__ out_loss) {
    const float m = __fdiv_rn(*loss_acc, 16777216.f);           // mean
    out_loss[0] = __fadd_rn(__fmul_rn(0.25f, m), m);            // beta*m + m
}

extern "C" void kernel_launch(void* const* d_in, const int* in_sizes, int n_in,
                              void* d_out, int out_size, void* d_ws, size_t ws_size,
                              hipStream_t stream) {
    const float* z = (const float*)d_in[0];        // [65536, 256]
    const float* e = (const float*)d_in[1];        // [256, 1024]

    float* out_zq   = (float*)d_out;                 // 16777216 floats
    float* out_idx  = out_zq + (size_t)NROWS * DDIM; // 65536 floats (index values)
    float* out_loss = out_idx + NROWS;               // 1 float

    float* loss_acc = (float*)d_ws;                            // 4 B
    float* enorm    = (float*)((char*)d_ws + 256);             // 4 KiB
    float* eT       = (float*)((char*)d_ws + 8192);            // 1 MiB

    enorm_kernel<<<KCODES / 256, 256, 0, stream>>>(e, enorm, loss_acc);
    etrans_kernel<<<dim3(KCODES / 64, DDIM / 64), 256, 0, stream>>>(e, eT);
    vq_main<<<NROWS / BM, NT, 0, stream>>>(z, e, enorm, eT, out_zq, out_idx, loss_acc);
    finalize_kernel<<<1, 1, 0, stream>>>(loss_acc, out_loss);
}

// Round 5
// 601.512 us; speedup vs baseline: 1.0812x; 1.0812x over previous
//
#include <hip/hip_runtime.h>
#include <math.h>

#define KCODES 1024
#define DDIM   256
#define NROWS  65536
#define BM     64
#define NT     512

typedef float f4 __attribute__((ext_vector_type(4)));

// LDS layout for the z-tile: element (d, r) at
//   d*64 + ((r>>2) ^ ((d>>2)&15))*4 + (r&3)
// Inner-loop read (fixed d, row-group g): b128 at ((g ^ tt)<<2) — wave-uniform
// address -> LDS broadcast, conflict-free.
__device__ __forceinline__ int swz(int d, int r) {
    return (d << 6) + ((((r) >> 2) ^ ((d >> 2) & 15)) << 2) + (r & 3);
}

// ||e_k||^2 sequential over d (matches np axis-0 row-by-row reduce) + zero loss acc
__global__ __launch_bounds__(256) void enorm_kernel(const float* __restrict__ e,
                                                    float* __restrict__ enorm,
                                                    float* __restrict__ loss_acc) {
    const int k = blockIdx.x * 256 + threadIdx.x;
    if (k == 0) *loss_acc = 0.f;
    float s = 0.f;
    for (int d = 0; d < DDIM; ++d) {
        const float v = e[(size_t)d * KCODES + k];
        s = __fadd_rn(s, __fmul_rn(v, v));
    }
    enorm[k] = s;
}

// LDS-tiled transpose: eT[k][d] = e[d][k]; f4 reads AND f4 writes (one-time)
__global__ __launch_bounds__(256) void etrans_kernel(const float* __restrict__ e,
                                                     float* __restrict__ eT) {
    __shared__ float tile[64][65];
    const int k0 = blockIdx.x << 6;
    const int d0 = blockIdx.y << 6;
    const int tr = threadIdx.x >> 4;
    const int tc = threadIdx.x & 15;
    #pragma unroll
    for (int p = 0; p < 4; ++p) {
        const int d = (p << 4) + tr;
        const f4 v = *reinterpret_cast<const f4*>(e + (size_t)(d0 + d) * KCODES + k0 + (tc << 2));
        tile[(tc << 2) + 0][d] = v[0];
        tile[(tc << 2) + 1][d] = v[1];
        tile[(tc << 2) + 2][d] = v[2];
        tile[(tc << 2) + 3][d] = v[3];
    }
    __syncthreads();
    #pragma unroll
    for (int p = 0; p < 4; ++p) {
        const int k = (p << 4) + tr;
        f4 w;
        w[0] = tile[k][(tc << 2) + 0];
        w[1] = tile[k][(tc << 2) + 1];
        w[2] = tile[k][(tc << 2) + 2];
        w[3] = tile[k][(tc << 2) + 3];
        *reinterpret_cast<f4*>(eT + (size_t)(k0 + k) * DDIM + d0 + (tc << 2)) = w;
    }
}

__global__ __launch_bounds__(NT, 4) void vq_main(const float* __restrict__ z,
                                                 const float* __restrict__ e,
                                                 const float* __restrict__ enorm,
                                                 const float* __restrict__ eT,
                                                 float* __restrict__ out_zq,
                                                 float* __restrict__ out_idx,
                                                 float* __restrict__ loss_acc) {
    __shared__ __align__(16) float A[DDIM * BM];  // 64 KiB z-tile, swizzled
    __shared__ float zn_s[BM];
    __shared__ int   kmin_s[BM];
    __shared__ float wsum_s[8];

    const int tid  = threadIdx.x;
    const int lane = tid & 63;
    const int wv   = tid >> 6;          // wave 0..7
    const int row0 = blockIdx.x * BM;

    // ---- stage z tile (wave reads 1 KiB contiguous per pass) ----
    for (int p = 0; p < 8; ++p) {
        const int row = p * 8 + wv;
        const int d0  = lane * 4;
        const f4 v = *reinterpret_cast<const f4*>(z + (size_t)(row0 + row) * DDIM + d0);
        A[swz(d0 + 0, row)] = v[0];
        A[swz(d0 + 1, row)] = v[1];
        A[swz(d0 + 2, row)] = v[2];
        A[swz(d0 + 3, row)] = v[3];
    }
    __syncthreads();

    // ---- ||z||^2 per row, numpy pairwise order (two 128-halves, 8 stride-8 partials) ----
    if (tid < BM) {
        const int r = tid;
        float hsum[2];
        #pragma unroll
        for (int h = 0; h < 2; ++h) {
            const int base = h * 128;
            float rp[8];
            #pragma unroll
            for (int j = 0; j < 8; ++j) {
                const float v = A[swz(base + j, r)];
                rp[j] = __fmul_rn(v, v);
            }
            for (int i = 8; i < 128; i += 8) {
                #pragma unroll
                for (int j = 0; j < 8; ++j) {
                    const float v = A[swz(base + i + j, r)];
                    rp[j] = __fadd_rn(rp[j], __fmul_rn(v, v));
                }
            }
            hsum[h] = __fadd_rn(__fadd_rn(__fadd_rn(rp[0], rp[1]), __fadd_rn(rp[2], rp[3])),
                                __fadd_rn(__fadd_rn(rp[4], rp[5]), __fadd_rn(rp[6], rp[7])));
        }
        zn_s[r] = __fadd_rn(hsum[0], hsum[1]);
    }
    __syncthreads();

    // ---- fused GEMM + running argmin ----
    // wave wv owns rows wv*8..wv*8+7 (A = 2 broadcast b128/d); lane owns 8
    // CONTIGUOUS cols (lane*8) of a 512-wide tile; 2 ct iterations cover K=1024.
    float rmin[8] = {INFINITY, INFINITY, INFINITY, INFINITY,
                     INFINITY, INFINITY, INFINITY, INFINITY};
    int   ridx[8] = {0, 0, 0, 0, 0, 0, 0, 0};

    const int g0 = wv << 1;            // row-group of rows wv*8..+3
    for (int ct = 0; ct < 2; ++ct) {
        const int c0 = (ct << 9) + (lane << 3);      // lane's 8 cols
        const char* bp0 = (const char*)(e + c0);     // d row:   +4096 B per d
        const char* bp1 = bp0 + 4096;                // d+1 row

        float acc[8][8];               // [row][col]
        #pragma unroll
        for (int r = 0; r < 8; ++r)
            #pragma unroll
            for (int i = 0; i < 8; ++i) acc[r][i] = 0.f;

        for (int db = 0; db < DDIM; db += 2) {
            const f4 b00 = *reinterpret_cast<const f4*>(bp0);       // d,   cols 0-3
            const f4 b01 = *reinterpret_cast<const f4*>(bp0 + 16);  // d,   cols 4-7
            const f4 b10 = *reinterpret_cast<const f4*>(bp1);       // d+1, cols 0-3
            const f4 b11 = *reinterpret_cast<const f4*>(bp1 + 16);  // d+1, cols 4-7
            bp0 += 8192; bp1 += 8192;

            {
                const int d  = db;
                const int tt = (d >> 2) & 15;
                const f4 a0 = *reinterpret_cast<const f4*>(&A[(d << 6) + (((g0 | 0) ^ tt) << 2)]);
                const f4 a1 = *reinterpret_cast<const f4*>(&A[(d << 6) + (((g0 | 1) ^ tt) << 2)]);
                #pragma unroll
                for (int r = 0; r < 4; ++r)
                    #pragma unroll
                    for (int i = 0; i < 4; ++i) {
                        acc[r][i]         = fmaf(a0[r], b00[i], acc[r][i]);
                        acc[r][4 + i]     = fmaf(a0[r], b01[i], acc[r][4 + i]);
                        acc[4 + r][i]     = fmaf(a1[r], b00[i], acc[4 + r][i]);
                        acc[4 + r][4 + i] = fmaf(a1[r], b01[i], acc[4 + r][4 + i]);
                    }
            }
            {
                const int d  = db + 1;
                const int tt = (d >> 2) & 15;
                const f4 a0 = *reinterpret_cast<const f4*>(&A[(d << 6) + (((g0 | 0) ^ tt) << 2)]);
                const f4 a1 = *reinterpret_cast<const f4*>(&A[(d << 6) + (((g0 | 1) ^ tt) << 2)]);
                #pragma unroll
                for (int r = 0; r < 4; ++r)
                    #pragma unroll
                    for (int i = 0; i < 4; ++i) {
                        acc[r][i]         = fmaf(a0[r], b10[i], acc[r][i]);
                        acc[r][4 + i]     = fmaf(a0[r], b11[i], acc[r][4 + i]);
                        acc[4 + r][i]     = fmaf(a1[r], b10[i], acc[4 + r][i]);
                        acc[4 + r][4 + i] = fmaf(a1[r], b11[i], acc[4 + r][4 + i]);
                    }
            }
        }

        // epilogue: s = fl(fl(zn + en) - 2*dot); candidates ascend per thread
        // (i ascending, then ct), so strict < = first-min
        const f4 en0 = *reinterpret_cast<const f4*>(enorm + c0);
        const f4 en1 = *reinterpret_cast<const f4*>(enorm + c0 + 4);
        #pragma unroll
        for (int r8 = 0; r8 < 8; ++r8) {
            const float zn = zn_s[(wv << 3) + r8];
            #pragma unroll
            for (int i = 0; i < 4; ++i) {
                const float t = __fadd_rn(zn, en0[i]);
                const float s = __fmaf_rn(-2.f, acc[r8][i], t);
                if (s < rmin[r8]) { rmin[r8] = s; ridx[r8] = c0 + i; }
            }
            #pragma unroll
            for (int i = 0; i < 4; ++i) {
                const float t = __fadd_rn(zn, en1[i]);
                const float s = __fmaf_rn(-2.f, acc[r8][4 + i], t);
                if (s < rmin[r8]) { rmin[r8] = s; ridx[r8] = c0 + 4 + i; }
            }
        }
    }

    // ---- per-row argmin reduce across 64 lanes (value, then min index on ties) ----
    #pragma unroll
    for (int r8 = 0; r8 < 8; ++r8) {
        float bv = rmin[r8];
        int   bi = ridx[r8];
        #pragma unroll
        for (int mask = 32; mask >= 1; mask >>= 1) {
            const float ov = __shfl_xor(bv, mask);
            const int   oi = __shfl_xor(bi, mask);
            if (ov < bv || (ov == bv && oi < bi)) { bv = ov; bi = oi; }
        }
        if (lane == 0) {
            const int row = (wv << 3) + r8;
            kmin_s[row] = bi;
            out_idx[row0 + row] = (float)bi;
        }
    }
    __syncthreads();

    // ---- gather z_q rows (coalesced via eT), write out, accumulate loss ----
    float part = 0.f;
    for (int p = 0; p < 8; ++p) {
        const int row = p * 8 + wv;
        const int d0  = lane * 4;
        const int kk  = kmin_s[row];
        const f4 q = *reinterpret_cast<const f4*>(eT + (size_t)kk * DDIM + d0);
        const float z0 = A[swz(d0 + 0, row)];
        const float z1 = A[swz(d0 + 1, row)];
        const float z2 = A[swz(d0 + 2, row)];
        const float z3 = A[swz(d0 + 3, row)];
        float dx;
        dx = q[0] - z0; part = fmaf(dx, dx, part);
        dx = q[1] - z1; part = fmaf(dx, dx, part);
        dx = q[2] - z2; part = fmaf(dx, dx, part);
        dx = q[3] - z3; part = fmaf(dx, dx, part);
        *reinterpret_cast<f4*>(out_zq + (size_t)(row0 + row) * DDIM + d0) = q;
    }
    #pragma unroll
    for (int off = 32; off > 0; off >>= 1) part += __shfl_down(part, off);
    if (lane == 0) wsum_s[wv] = part;
    __syncthreads();
    if (tid == 0) {
        float s = 0.f;
        #pragma unroll
        for (int i = 0; i < 8; ++i) s += wsum_s[i];
        atomicAdd(loss_acc, s);
    }
}

__global__ void finalize_kernel(const float* __restrict__ loss_acc,
                                float* __restrict__ out_loss) {
    const float m = __fdiv_rn(*loss_acc, 16777216.f);           // mean
    out_loss[0] = __fadd_rn(__fmul_rn(0.25f, m), m);            // beta*m + m
}

extern "C" void kernel_launch(void* const* d_in, const int* in_sizes, int n_in,
                              void* d_out, int out_size, void* d_ws, size_t ws_size,
                              hipStream_t stream) {
    const float* z = (const float*)d_in[0];        // [65536, 256]
    const float* e = (const float*)d_in[1];        // [256, 1024]

    float* out_zq   = (float*)d_out;                 // 16777216 floats
    float* out_idx  = out_zq + (size_t)NROWS * DDIM; // 65536 floats (index values)
    float* out_loss = out_idx + NROWS;               // 1 float

    float* loss_acc = (float*)d_ws;                            // 4 B
    float* enorm    = (float*)((char*)d_ws + 256);             // 4 KiB
    float* eT       = (float*)((char*)d_ws + 8192);            // 1 MiB

    enorm_kernel<<<KCODES / 256, 256, 0, stream>>>(e, enorm, loss_acc);
    etrans_kernel<<<dim3(KCODES / 64, DDIM / 64), 256, 0, stream>>>(e, eT);
    vq_main<<<NROWS / BM, NT, 0, stream>>>(z, e, enorm, eT, out_zq, out_idx, loss_acc);
    finalize_kernel<<<1, 1, 0, stream>>>(loss_acc, out_loss);
}

// Round 6
// 565.580 us; speedup vs baseline: 1.1498x; 1.0635x over previous
//
#include <hip/hip_runtime.h>
#include <math.h>

#define KCODES 1024
#define DDIM   256
#define NROWS  65536
#define BM     64
#define NT     512

typedef float f4 __attribute__((ext_vector_type(4)));

// LDS layout for the z-tile: element (d, r) at
//   d*64 + ((r>>2) ^ ((d>>2)&15))*4 + (r&3)
// Inner-loop read (fixed d, row-group g): b128 at ((g ^ tt)<<2) — wave-uniform
// address -> LDS broadcast, conflict-free.
__device__ __forceinline__ int swz(int d, int r) {
    return (d << 6) + ((((r) >> 2) ^ ((d >> 2) & 15)) << 2) + (r & 3);
}

// ||e_k||^2 sequential over d (matches np axis-0 row-by-row reduce) + zero loss acc
__global__ __launch_bounds__(256) void enorm_kernel(const float* __restrict__ e,
                                                    float* __restrict__ enorm,
                                                    float* __restrict__ loss_acc) {
    const int k = blockIdx.x * 256 + threadIdx.x;
    if (k == 0) *loss_acc = 0.f;
    float s = 0.f;
    for (int d = 0; d < DDIM; ++d) {
        const float v = e[(size_t)d * KCODES + k];
        s = __fadd_rn(s, __fmul_rn(v, v));
    }
    enorm[k] = s;
}

// LDS-tiled transpose: eT[k][d] = e[d][k]; f4 reads AND f4 writes (one-time)
__global__ __launch_bounds__(256) void etrans_kernel(const float* __restrict__ e,
                                                     float* __restrict__ eT) {
    __shared__ float tile[64][65];
    const int k0 = blockIdx.x << 6;
    const int d0 = blockIdx.y << 6;
    const int tr = threadIdx.x >> 4;
    const int tc = threadIdx.x & 15;
    #pragma unroll
    for (int p = 0; p < 4; ++p) {
        const int d = (p << 4) + tr;
        const f4 v = *reinterpret_cast<const f4*>(e + (size_t)(d0 + d) * KCODES + k0 + (tc << 2));
        tile[(tc << 2) + 0][d] = v[0];
        tile[(tc << 2) + 1][d] = v[1];
        tile[(tc << 2) + 2][d] = v[2];
        tile[(tc << 2) + 3][d] = v[3];
    }
    __syncthreads();
    #pragma unroll
    for (int p = 0; p < 4; ++p) {
        const int k = (p << 4) + tr;
        f4 w;
        w[0] = tile[k][(tc << 2) + 0];
        w[1] = tile[k][(tc << 2) + 1];
        w[2] = tile[k][(tc << 2) + 2];
        w[3] = tile[k][(tc << 2) + 3];
        *reinterpret_cast<f4*>(eT + (size_t)(k0 + k) * DDIM + d0 + (tc << 2)) = w;
    }
}

// launch_bounds(512, 2): R2-R5 used (512,4), which the backend treated as an
// 8-waves/SIMD target -> 64-VGPR cap -> acc[8][8] spilled to scratch
// (+211 MB WRITE, +100 MB FETCH vs ideal, VGPR_Count=64). LDS (66.5 KiB)
// caps us at 2 blocks/CU regardless, so allow >=128 VGPRs.
__global__ __launch_bounds__(NT, 2) void vq_main(const float* __restrict__ z,
                                                 const float* __restrict__ e,
                                                 const float* __restrict__ enorm,
                                                 const float* __restrict__ eT,
                                                 float* __restrict__ out_zq,
                                                 float* __restrict__ out_idx,
                                                 float* __restrict__ loss_acc) {
    __shared__ __align__(16) float A[DDIM * BM];  // 64 KiB z-tile, swizzled
    __shared__ float zn_s[BM];
    __shared__ int   kmin_s[BM];
    __shared__ float wsum_s[8];

    const int tid  = threadIdx.x;
    const int lane = tid & 63;
    const int wv   = tid >> 6;          // wave 0..7
    const int row0 = blockIdx.x * BM;

    // ---- stage z tile (wave reads 1 KiB contiguous per pass) ----
    for (int p = 0; p < 8; ++p) {
        const int row = p * 8 + wv;
        const int d0  = lane * 4;
        const f4 v = *reinterpret_cast<const f4*>(z + (size_t)(row0 + row) * DDIM + d0);
        A[swz(d0 + 0, row)] = v[0];
        A[swz(d0 + 1, row)] = v[1];
        A[swz(d0 + 2, row)] = v[2];
        A[swz(d0 + 3, row)] = v[3];
    }
    __syncthreads();

    // ---- ||z||^2 per row, numpy pairwise order (two 128-halves, 8 stride-8 partials) ----
    if (tid < BM) {
        const int r = tid;
        float hsum[2];
        #pragma unroll
        for (int h = 0; h < 2; ++h) {
            const int base = h * 128;
            float rp[8];
            #pragma unroll
            for (int j = 0; j < 8; ++j) {
                const float v = A[swz(base + j, r)];
                rp[j] = __fmul_rn(v, v);
            }
            for (int i = 8; i < 128; i += 8) {
                #pragma unroll
                for (int j = 0; j < 8; ++j) {
                    const float v = A[swz(base + i + j, r)];
                    rp[j] = __fadd_rn(rp[j], __fmul_rn(v, v));
                }
            }
            hsum[h] = __fadd_rn(__fadd_rn(__fadd_rn(rp[0], rp[1]), __fadd_rn(rp[2], rp[3])),
                                __fadd_rn(__fadd_rn(rp[4], rp[5]), __fadd_rn(rp[6], rp[7])));
        }
        zn_s[r] = __fadd_rn(hsum[0], hsum[1]);
    }
    __syncthreads();

    // ---- fused GEMM + running argmin ----
    // wave wv owns rows wv*8..wv*8+7 (A = 2 broadcast b128/d); lane owns 8
    // CONTIGUOUS cols (lane*8) of a 512-wide tile; 2 ct iterations cover K=1024.
    float rmin[8] = {INFINITY, INFINITY, INFINITY, INFINITY,
                     INFINITY, INFINITY, INFINITY, INFINITY};
    int   ridx[8] = {0, 0, 0, 0, 0, 0, 0, 0};

    const int g0 = wv << 1;            // row-group of rows wv*8..+3
    for (int ct = 0; ct < 2; ++ct) {
        const int c0 = (ct << 9) + (lane << 3);      // lane's 8 cols
        const char* bp0 = (const char*)(e + c0);     // d row:   +4096 B per d
        const char* bp1 = bp0 + 4096;                // d+1 row

        float acc[8][8];               // [row][col]
        #pragma unroll
        for (int r = 0; r < 8; ++r)
            #pragma unroll
            for (int i = 0; i < 8; ++i) acc[r][i] = 0.f;

        for (int db = 0; db < DDIM; db += 2) {
            const f4 b00 = *reinterpret_cast<const f4*>(bp0);       // d,   cols 0-3
            const f4 b01 = *reinterpret_cast<const f4*>(bp0 + 16);  // d,   cols 4-7
            const f4 b10 = *reinterpret_cast<const f4*>(bp1);       // d+1, cols 0-3
            const f4 b11 = *reinterpret_cast<const f4*>(bp1 + 16);  // d+1, cols 4-7
            bp0 += 8192; bp1 += 8192;

            {
                const int d  = db;
                const int tt = (d >> 2) & 15;
                const f4 a0 = *reinterpret_cast<const f4*>(&A[(d << 6) + (((g0 | 0) ^ tt) << 2)]);
                const f4 a1 = *reinterpret_cast<const f4*>(&A[(d << 6) + (((g0 | 1) ^ tt) << 2)]);
                #pragma unroll
                for (int r = 0; r < 4; ++r)
                    #pragma unroll
                    for (int i = 0; i < 4; ++i) {
                        acc[r][i]         = fmaf(a0[r], b00[i], acc[r][i]);
                        acc[r][4 + i]     = fmaf(a0[r], b01[i], acc[r][4 + i]);
                        acc[4 + r][i]     = fmaf(a1[r], b00[i], acc[4 + r][i]);
                        acc[4 + r][4 + i] = fmaf(a1[r], b01[i], acc[4 + r][4 + i]);
                    }
            }
            {
                const int d  = db + 1;
                const int tt = (d >> 2) & 15;
                const f4 a0 = *reinterpret_cast<const f4*>(&A[(d << 6) + (((g0 | 0) ^ tt) << 2)]);
                const f4 a1 = *reinterpret_cast<const f4*>(&A[(d << 6) + (((g0 | 1) ^ tt) << 2)]);
                #pragma unroll
                for (int r = 0; r < 4; ++r)
                    #pragma unroll
                    for (int i = 0; i < 4; ++i) {
                        acc[r][i]         = fmaf(a0[r], b10[i], acc[r][i]);
                        acc[r][4 + i]     = fmaf(a0[r], b11[i], acc[r][4 + i]);
                        acc[4 + r][i]     = fmaf(a1[r], b10[i], acc[4 + r][i]);
                        acc[4 + r][4 + i] = fmaf(a1[r], b11[i], acc[4 + r][4 + i]);
                    }
            }
        }

        // epilogue: s = fl(fl(zn + en) - 2*dot); candidates ascend per thread
        // (i ascending, then ct), so strict < = first-min
        const f4 en0 = *reinterpret_cast<const f4*>(enorm + c0);
        const f4 en1 = *reinterpret_cast<const f4*>(enorm + c0 + 4);
        #pragma unroll
        for (int r8 = 0; r8 < 8; ++r8) {
            const float zn = zn_s[(wv << 3) + r8];
            #pragma unroll
            for (int i = 0; i < 4; ++i) {
                const float t = __fadd_rn(zn, en0[i]);
                const float s = __fmaf_rn(-2.f, acc[r8][i], t);
                if (s < rmin[r8]) { rmin[r8] = s; ridx[r8] = c0 + i; }
            }
            #pragma unroll
            for (int i = 0; i < 4; ++i) {
                const float t = __fadd_rn(zn, en1[i]);
                const float s = __fmaf_rn(-2.f, acc[r8][4 + i], t);
                if (s < rmin[r8]) { rmin[r8] = s; ridx[r8] = c0 + 4 + i; }
            }
        }
    }

    // ---- per-row argmin reduce across 64 lanes (value, then min index on ties) ----
    #pragma unroll
    for (int r8 = 0; r8 < 8; ++r8) {
        float bv = rmin[r8];
        int   bi = ridx[r8];
        #pragma unroll
        for (int mask = 32; mask >= 1; mask >>= 1) {
            const float ov = __shfl_xor(bv, mask);
            const int   oi = __shfl_xor(bi, mask);
            if (ov < bv || (ov == bv && oi < bi)) { bv = ov; bi = oi; }
        }
        if (lane == 0) {
            const int row = (wv << 3) + r8;
            kmin_s[row] = bi;
            out_idx[row0 + row] = (float)bi;
        }
    }
    __syncthreads();

    // ---- gather z_q rows (coalesced via eT), write out, accumulate loss ----
    float part = 0.f;
    for (int p = 0; p < 8; ++p) {
        const int row = p * 8 + wv;
        const int d0  = lane * 4;
        const int kk  = kmin_s[row];
        const f4 q = *reinterpret_cast<const f4*>(eT + (size_t)kk * DDIM + d0);
        const float z0 = A[swz(d0 + 0, row)];
        const float z1 = A[swz(d0 + 1, row)];
        const float z2 = A[swz(d0 + 2, row)];
        const float z3 = A[swz(d0 + 3, row)];
        float dx;
        dx = q[0] - z0; part = fmaf(dx, dx, part);
        dx = q[1] - z1; part = fmaf(dx, dx, part);
        dx = q[2] - z2; part = fmaf(dx, dx, part);
        dx = q[3] - z3; part = fmaf(dx, dx, part);
        *reinterpret_cast<f4*>(out_zq + (size_t)(row0 + row) * DDIM + d0) = q;
    }
    #pragma unroll
    for (int off = 32; off > 0; off >>= 1) part += __shfl_down(part, off);
    if (lane == 0) wsum_s[wv] = part;
    __syncthreads();
    if (tid == 0) {
        float s = 0.f;
        #pragma unroll
        for (int i = 0; i < 8; ++i) s += wsum_s[i];
        atomicAdd(loss_acc, s);
    }
}

__global__ void finalize_kernel(const float* __restrict__ loss_acc,
                                float* __restrict__ out_loss) {
    const float m = __fdiv_rn(*loss_acc, 16777216.f);           // mean
    out_loss[0] = __fadd_rn(__fmul_rn(0.25f, m), m);            // beta*m + m
}

extern "C" void kernel_launch(void* const* d_in, const int* in_sizes, int n_in,
                              void* d_out, int out_size, void* d_ws, size_t ws_size,
                              hipStream_t stream) {
    const float* z = (const float*)d_in[0];        // [65536, 256]
    const float* e = (const float*)d_in[1];        // [256, 1024]

    float* out_zq   = (float*)d_out;                 // 16777216 floats
    float* out_idx  = out_zq + (size_t)NROWS * DDIM; // 65536 floats (index values)
    float* out_loss = out_idx + NROWS;               // 1 float

    float* loss_acc = (float*)d_ws;                            // 4 B
    float* enorm    = (float*)((char*)d_ws + 256);             // 4 KiB
    float* eT       = (float*)((char*)d_ws + 8192);            // 1 MiB

    enorm_kernel<<<KCODES / 256, 256, 0, stream>>>(e, enorm, loss_acc);
    etrans_kernel<<<dim3(KCODES / 64, DDIM / 64), 256, 0, stream>>>(e, eT);
    vq_main<<<NROWS / BM, NT, 0, stream>>>(z, e, enorm, eT, out_zq, out_idx, loss_acc);
    finalize_kernel<<<1, 1, 0, stream>>>(loss_acc, out_loss);
}